// Round 1
// baseline (60.205 us; speedup 1.0000x reference)
//
#include <hip/hip_runtime.h>
#include <math.h>

// ---------------- problem constants ----------------
constexpr int B  = 2, C = 64, H = 128, W = 128;
constexpr int Cr = 16;           // reduced channels
constexpr int K  = 7, KK = 49;   // kernel taps
constexpr int HW  = H * W;       // 16384
constexpr int CHW = C * HW;      // 1048576
constexpr int NPIX = B * HW;     // 32768
constexpr float EPS = 1e-5f;

// LDS partition for the involution kernel (floats)
constexpr int XS_F  = C * 196;   // 64 ch x 14x14 halo tile   = 12544
constexpr int KC_F  = KK * 64;   // 49 taps x 64 pixels       = 3136
constexpr int ACT_F = Cr * 64;   //                           = 1024
constexpr int WR_F  = Cr * C;    //                           = 1024
constexpr int WSP_F = KK * Cr;   //                           = 784
constexpr int SMEM_F = XS_F + KC_F + ACT_F + WR_F + WSP_F + KK + Cr + Cr; // 18593
constexpr int SMEM_BYTES = SMEM_F * 4;   // 74372 B -> 2 blocks/CU

// ws layout (floats): [0,8192) per-block partials (256 x 32); [8192,8224) stats
// ---------------------------------------------------

// Kernel 1: reduced = X . w_reduce + b_reduce; per-block partial sum/sumsq per channel.
__global__ __launch_bounds__(128) void k_reduce_stats(
    const float* __restrict__ X, const float* __restrict__ w_reduce,
    const float* __restrict__ b_reduce, float* __restrict__ partial)
{
    __shared__ float wr[WR_F];
    __shared__ float brd[Cr];
    __shared__ float tmp[2][32];
    const int t = threadIdx.x;
    for (int i = t; i < WR_F; i += 128) wr[i] = w_reduce[i];
    if (t < Cr) brd[t] = b_reduce[t];
    __syncthreads();

    const int p  = blockIdx.x * 128 + t;   // 0..32767 : one pixel per thread
    const int b  = p >> 14;
    const int hw = p & (HW - 1);
    const float* xb = X + b * CHW + hw;

    float r[Cr];
    #pragma unroll
    for (int o = 0; o < Cr; ++o) r[o] = brd[o];
    #pragma unroll 4
    for (int c = 0; c < C; ++c) {
        const float x = xb[c * HW];            // coalesced across lanes
        #pragma unroll
        for (int o = 0; o < Cr; ++o) r[o] = fmaf(x, wr[o * C + c], r[o]);
    }

    const int lane = t & 63, wv = t >> 6;
    #pragma unroll
    for (int o = 0; o < Cr; ++o) {
        float s = r[o];
        float q = r[o] * r[o];
        #pragma unroll
        for (int off = 32; off > 0; off >>= 1) {
            s += __shfl_down(s, off);
            q += __shfl_down(q, off);
        }
        if (lane == 0) { tmp[wv][o] = s; tmp[wv][Cr + o] = q; }
    }
    __syncthreads();
    if (t < 32) partial[blockIdx.x * 32 + t] = tmp[0][t] + tmp[1][t];
}

// Kernel 2: fixed-order reduction of partials -> mean, rstd (deterministic).
__global__ __launch_bounds__(256) void k_stats_final(
    const float* __restrict__ partial, float* __restrict__ stats)
{
    __shared__ float buf[256 * 32];
    __shared__ float red[256];
    __shared__ float fin[32];
    const int t = threadIdx.x;
    for (int i = t; i < 256 * 32; i += 256) buf[i] = partial[i];
    __syncthreads();
    const int o = t & 31, g = t >> 5;   // 8 groups of 32 blocks each
    float acc = 0.f;
    #pragma unroll 8
    for (int j = 0; j < 32; ++j) acc += buf[(g * 32 + j) * 32 + o];
    red[t] = acc;
    __syncthreads();
    if (t < 32) {
        float v = 0.f;
        #pragma unroll
        for (int g2 = 0; g2 < 8; ++g2) v += red[g2 * 32 + t];
        fin[t] = v;
    }
    __syncthreads();
    if (t < Cr) {
        const float mean = fin[t] / (float)NPIX;
        const float var  = fin[Cr + t] / (float)NPIX - mean * mean;  // biased, = jnp.var
        stats[t]      = mean;
        stats[Cr + t] = rsqrtf(var + EPS);
    }
}

// Kernel 3: fused coef-gen + involution. Block = (b, 8x8 spatial tile), all 64 channels.
__global__ __launch_bounds__(256) void k_involution(
    const float* __restrict__ X, const float* __restrict__ w_reduce,
    const float* __restrict__ b_reduce, const float* __restrict__ gamma,
    const float* __restrict__ beta, const float* __restrict__ w_span,
    const float* __restrict__ b_span, const float* __restrict__ stats,
    float* __restrict__ out)
{
    extern __shared__ float smem[];
    float* Xs   = smem;              // [c][r*14+col], r,col in 0..13
    float* kcS  = Xs  + XS_F;        // [k][pix]
    float* actS = kcS + KC_F;        // [o][pix]
    float* wrS  = actS + ACT_F;      // [o][c]
    float* wspS = wrS + WR_F;        // [k][o]
    float* bspS = wspS + WSP_F;      // [k]
    float* scS  = bspS + KK;         // folded BN scale
    float* ofS  = scS + Cr;          // folded BN offset

    const int t    = threadIdx.x;
    const int bx   = blockIdx.x;
    const int b    = bx >> 8;
    const int tile = bx & 255;
    const int h0   = (tile >> 4) << 3;
    const int w0   = (tile & 15) << 3;

    // ---- phase 0: stage X halo tile + weights ----
    const float* xbg = X + b * CHW;
    for (int idx = t; idx < XS_F; idx += 256) {
        const int c   = idx / 196;
        const int rem = idx - c * 196;
        const int r   = rem / 14;
        const int col = rem - r * 14;
        const int gh  = h0 + r - 3, gw = w0 + col - 3;
        float v = 0.f;
        if ((unsigned)gh < (unsigned)H && (unsigned)gw < (unsigned)W)
            v = xbg[c * HW + gh * W + gw];
        Xs[idx] = v;
    }
    for (int i = t; i < WR_F;  i += 256) wrS[i]  = w_reduce[i];
    for (int i = t; i < WSP_F; i += 256) wspS[i] = w_span[i];
    if (t < KK) bspS[t] = b_span[t];
    if (t < Cr) {
        const float m  = stats[t];
        const float rs = stats[Cr + t];
        const float gm = gamma[t];
        scS[t] = gm * rs;
        ofS[t] = (b_reduce[t] - m) * gm * rs + beta[t];
    }
    __syncthreads();

    const int pix = t & 63;          // 8x8 tile pixel
    const int grp = t >> 6;          // 0..3
    const int ph  = pix >> 3, pw = pix & 7;

    // ---- phase 1: act = relu(BN(X . w_reduce + b_reduce)) at center pixels ----
    {
        const int base = (ph + 3) * 14 + (pw + 3);
        float d0 = 0.f, d1 = 0.f, d2 = 0.f, d3 = 0.f;
        #pragma unroll 8
        for (int c = 0; c < C; ++c) {
            const float x = Xs[c * 196 + base];
            d0 = fmaf(x, wrS[(grp * 4 + 0) * C + c], d0);
            d1 = fmaf(x, wrS[(grp * 4 + 1) * C + c], d1);
            d2 = fmaf(x, wrS[(grp * 4 + 2) * C + c], d2);
            d3 = fmaf(x, wrS[(grp * 4 + 3) * C + c], d3);
        }
        const float d[4] = {d0, d1, d2, d3};
        #pragma unroll
        for (int j = 0; j < 4; ++j) {
            const int o = grp * 4 + j;
            actS[o * 64 + pix] = fmaxf(fmaf(scS[o], d[j], ofS[o]), 0.f);
        }
    }
    __syncthreads();

    // ---- phase 2: 49 kernel coefficients per pixel ----
    for (int k = grp; k < KK; k += 4) {
        float v = bspS[k];
        #pragma unroll
        for (int o = 0; o < Cr; ++o)
            v = fmaf(actS[o * 64 + pix], wspS[k * Cr + o], v);
        kcS[k * 64 + pix] = v;
    }
    __syncthreads();

    // ---- phase 3: involution, 16 channels per thread ----
    float acc[16];
    #pragma unroll
    for (int i = 0; i < 16; ++i) acc[i] = 0.f;
    const float* xsc = Xs + grp * 16 * 196;
    #pragma unroll
    for (int k = 0; k < KK; ++k) {
        const int kh = k / 7, kw = k - (k / 7) * 7;   // compile-time after unroll
        const float kcv = kcS[k * 64 + pix];
        const int xoff = (ph + kh) * 14 + (pw + kw);
        #pragma unroll
        for (int i = 0; i < 16; ++i)
            acc[i] = fmaf(kcv, xsc[i * 196 + xoff], acc[i]);
    }
    float* ob = out + b * CHW + (grp * 16) * HW + (h0 + ph) * W + (w0 + pw);
    #pragma unroll
    for (int i = 0; i < 16; ++i) ob[i * HW] = acc[i];
}

extern "C" void kernel_launch(void* const* d_in, const int* in_sizes, int n_in,
                              void* d_out, int out_size, void* d_ws, size_t ws_size,
                              hipStream_t stream) {
    const float* X        = (const float*)d_in[0];
    const float* w_reduce = (const float*)d_in[1];
    const float* b_reduce = (const float*)d_in[2];
    const float* gamma    = (const float*)d_in[3];
    const float* beta     = (const float*)d_in[4];
    const float* w_span   = (const float*)d_in[5];
    const float* b_span   = (const float*)d_in[6];
    float* out = (float*)d_out;
    float* ws  = (float*)d_ws;

    float* partial = ws;          // 8192 floats
    float* stats   = ws + 8192;   // 32 floats

    hipFuncSetAttribute((const void*)k_involution,
                        hipFuncAttributeMaxDynamicSharedMemorySize, SMEM_BYTES);

    k_reduce_stats<<<256, 128, 0, stream>>>(X, w_reduce, b_reduce, partial);
    k_stats_final<<<1, 256, 0, stream>>>(partial, stats);
    k_involution<<<512, 256, SMEM_BYTES, stream>>>(
        X, w_reduce, b_reduce, gamma, beta, w_span, b_span, stats, out);
}

// Round 2
// 38.871 us; speedup vs baseline: 1.5488x; 1.5488x over previous
//
#include <hip/hip_runtime.h>
#include <math.h>

// ---------------- problem constants ----------------
constexpr int B  = 2, C = 64, H = 128, W = 128;
constexpr int Cr = 16;
constexpr int K  = 7, KK = 49;
constexpr int HW  = H * W;
constexpr int CHW = C * HW;
constexpr int NPIX = B * HW;       // 32768
constexpr float EPS = 1e-5f;

// ---- fast-path ws layout (floats): r[NPIX][16] | partial[512*32] | stats[32]
constexpr int R_F = NPIX * Cr;     // 524288
constexpr int P_F = 512 * 32;      // 16384
constexpr size_t WS_NEED = (size_t)(R_F + P_F + 64) * 4;

// ==================== FAST PATH ====================

// A: r = X . w_reduce + b_reduce  (+ per-block stats partials)
// grid 512 x 256: block = 64 pixels x 4 channel-groups(16ch). wave w == cgroup w.
__global__ __launch_bounds__(256) void k_reduce_r(
    const float* __restrict__ X, const float* __restrict__ w_reduce,
    const float* __restrict__ b_reduce, float* __restrict__ r_ws,
    float* __restrict__ partial)
{
    __shared__ float wrS[Cr * C];          // [o][c]
    __shared__ float tmpA[4][Cr][64];      // 16 KB exchange
    const int t = threadIdx.x;
    for (int i = t; i < Cr * C; i += 256) wrS[i] = w_reduce[i];
    __syncthreads();

    const int pixl = t & 63, cg = t >> 6;  // cg uniform per wave
    const int p = blockIdx.x * 64 + pixl;  // global pixel 0..32767
    const int b = p >> 14, hw = p & (HW - 1);
    const float* xb = X + (size_t)b * CHW + hw;

    float x[16];
    #pragma unroll
    for (int i = 0; i < 16; ++i) x[i] = xb[(cg * 16 + i) * HW];  // 16 indep strided loads

    float rp[16];
    #pragma unroll
    for (int o = 0; o < 16; ++o) rp[o] = (cg == 0) ? b_reduce[o] : 0.f;
    #pragma unroll
    for (int i = 0; i < 16; ++i) {
        const float xv = x[i];
        #pragma unroll
        for (int o = 0; o < 16; ++o)
            rp[o] = fmaf(xv, wrS[o * 64 + cg * 16 + i], rp[o]);  // wave-broadcast read
    }
    #pragma unroll
    for (int o = 0; o < 16; ++o) tmpA[cg][o][pixl] = rp[o];
    __syncthreads();

    float rr[4];
    #pragma unroll
    for (int j = 0; j < 4; ++j) {
        const int o = cg * 4 + j;
        rr[j] = tmpA[0][o][pixl] + tmpA[1][o][pixl] + tmpA[2][o][pixl] + tmpA[3][o][pixl];
    }
    *(float4*)&r_ws[(size_t)p * 16 + cg * 4] = make_float4(rr[0], rr[1], rr[2], rr[3]);

    float s[4], q[4];
    #pragma unroll
    for (int j = 0; j < 4; ++j) { s[j] = rr[j]; q[j] = rr[j] * rr[j]; }
    #pragma unroll
    for (int off = 32; off > 0; off >>= 1) {
        #pragma unroll
        for (int j = 0; j < 4; ++j) {
            s[j] += __shfl_down(s[j], off);
            q[j] += __shfl_down(q[j], off);
        }
    }
    if ((t & 63) == 0) {
        #pragma unroll
        for (int j = 0; j < 4; ++j) {
            partial[blockIdx.x * 32 + cg * 4 + j]      = s[j];
            partial[blockIdx.x * 32 + 16 + cg * 4 + j] = q[j];
        }
    }
}

// S: finalize stats -> folded BN scale/offset: stats[o]=gamma*rstd, stats[16+o]=beta-mean*that
__global__ __launch_bounds__(256) void k_stats2(
    const float* __restrict__ partial, const float* __restrict__ gamma,
    const float* __restrict__ beta, float* __restrict__ stats)
{
    __shared__ float red[8][32];
    __shared__ float fin[32];
    const int t = threadIdx.x;
    const int o = t & 31, seg = t >> 5;
    float acc = 0.f;
    #pragma unroll 16
    for (int j = 0; j < 64; ++j) acc += partial[(seg * 64 + j) * 32 + o];
    red[seg][o] = acc;
    __syncthreads();
    if (t < 32) {
        float v = 0.f;
        #pragma unroll
        for (int g = 0; g < 8; ++g) v += red[g][t];
        fin[t] = v;
    }
    __syncthreads();
    if (t < 16) {
        const float mean = fin[t] / (float)NPIX;
        const float var  = fin[16 + t] / (float)NPIX - mean * mean;
        const float sc   = gamma[t] * rsqrtf(var + EPS);
        stats[t]      = sc;
        stats[16 + t] = beta[t] - mean * sc;
    }
}

// C: fused act/kc + involution, channel-split.
// grid 1024 = [b][half][256 tiles], XCD-swizzled. block 256, LDS 49.3 KB -> 3 blocks/CU.
constexpr int CSP = 228;   // Xs channel stride (14*16 + 4 pad; 228%32=4 spreads banks)
constexpr int RPT = 16;    // row pitch

__global__ __launch_bounds__(256) void k_inv_split(
    const float* __restrict__ X, const float* __restrict__ r_ws,
    const float* __restrict__ stats, const float* __restrict__ w_span,
    const float* __restrict__ b_span, float* __restrict__ out)
{
    __shared__ float Xs[32 * CSP];     // 29184 B
    __shared__ float kcS[KK * 64];     // 12544 B
    __shared__ float actS[Cr * 64];    // 4096 B
    __shared__ float wspS[KK * Cr];    // 3136 B
    __shared__ float bspS[KK];
    __shared__ float scS[Cr], ofS[Cr];

    const int t   = threadIdx.x;
    const int raw = blockIdx.x;
    const int wg  = (raw & 7) * 128 + (raw >> 3);   // bijective XCD swizzle (1024%8==0)
    const int tile = wg & 255;
    const int half = (wg >> 8) & 1;
    const int b    = wg >> 9;
    const int h0 = (tile >> 4) << 3, w0 = (tile & 15) << 3;

    // ---- ph0: stage X halo (this block's 32 channels), weights, BN consts ----
    const float* xbg = X + (size_t)b * CHW + (half * 32) * HW;
    for (int idx = t; idx < 32 * 196; idx += 256) {
        const int c = idx / 196, rem = idx - c * 196;
        const int r = rem / 14,  col = rem - r * 14;
        const int gh = h0 + r - 3, gw = w0 + col - 3;
        float v = 0.f;
        if ((unsigned)gh < (unsigned)H && (unsigned)gw < (unsigned)W)
            v = xbg[c * HW + gh * W + gw];
        Xs[c * CSP + r * RPT + col] = v;
    }
    for (int i = t; i < KK * Cr; i += 256) wspS[i] = w_span[i];
    if (t < KK) bspS[t] = b_span[t];
    if (t < Cr) { scS[t] = stats[t]; ofS[t] = stats[16 + t]; }

    const int pixl = t & 63, qo = t >> 6;          // qo uniform per wave
    const int php = pixl >> 3, pwp = pixl & 7;
    const int pixg = b * HW + (h0 + php) * W + (w0 + pwp);
    const float4 r4 = *(const float4*)&r_ws[(size_t)pixg * 16 + qo * 4];
    __syncthreads();

    // ---- ph1: act = relu(sc*r + of) ----
    {
        const float rv[4] = {r4.x, r4.y, r4.z, r4.w};
        #pragma unroll
        for (int j = 0; j < 4; ++j) {
            const int o = qo * 4 + j;
            actS[o * 64 + pixl] = fmaxf(fmaf(scS[o], rv[j], ofS[o]), 0.f);
        }
    }
    __syncthreads();

    // ---- ph2: kc coefficients ----
    {
        float act[16];
        #pragma unroll
        for (int o = 0; o < 16; ++o) act[o] = actS[o * 64 + pixl];
        for (int k = qo; k < KK; k += 4) {          // k uniform per wave
            float v = bspS[k];
            #pragma unroll
            for (int o = 0; o < 16; ++o) v = fmaf(act[o], wspS[k * 16 + o], v);
            kcS[k * 64 + pixl] = v;
        }
    }
    __syncthreads();

    // ---- ph3: involution. thread = 4-px strip x 2 channels ----
    const int st  = t & 15, cgl = t >> 4;
    const int ph3r = st >> 1, pw0 = (st & 1) * 4;
    const int c0 = cgl * 2;
    float acc[2][4];
    #pragma unroll
    for (int i = 0; i < 2; ++i)
        #pragma unroll
        for (int px = 0; px < 4; ++px) acc[i][px] = 0.f;

    #pragma unroll
    for (int kh = 0; kh < 7; ++kh) {
        float4 kcr[7];
        #pragma unroll
        for (int kw = 0; kw < 7; ++kw)
            kcr[kw] = *(const float4*)&kcS[(kh * 7 + kw) * 64 + st * 4];  // 4-lane broadcast
        const float* kf = (const float*)kcr;
        #pragma unroll
        for (int i = 0; i < 2; ++i) {
            const float* xr = &Xs[(c0 + i) * CSP + (ph3r + kh) * RPT + pw0];
            const float4 xa = *(const float4*)&xr[0];
            const float4 xb4 = *(const float4*)&xr[4];
            const float4 xc = *(const float4*)&xr[8];
            const float xw[12] = {xa.x, xa.y, xa.z, xa.w,
                                  xb4.x, xb4.y, xb4.z, xb4.w,
                                  xc.x, xc.y, xc.z, xc.w};
            #pragma unroll
            for (int kw = 0; kw < 7; ++kw)
                #pragma unroll
                for (int px = 0; px < 4; ++px)
                    acc[i][px] = fmaf(kf[kw * 4 + px], xw[kw + px], acc[i][px]);
        }
    }

    float* ob = out + (size_t)b * CHW + (size_t)(half * 32 + c0) * HW
                    + (h0 + ph3r) * W + (w0 + pw0);
    *(float4*)&ob[0]  = make_float4(acc[0][0], acc[0][1], acc[0][2], acc[0][3]);
    *(float4*)&ob[HW] = make_float4(acc[1][0], acc[1][1], acc[1][2], acc[1][3]);
}

// ==================== FALLBACK PATH (round-1, passing) ====================

constexpr int XS_F  = C * 196;
constexpr int KC_F  = KK * 64;
constexpr int ACT_F = Cr * 64;
constexpr int WR_F  = Cr * C;
constexpr int WSP_F = KK * Cr;
constexpr int SMEM_F = XS_F + KC_F + ACT_F + WR_F + WSP_F + KK + Cr + Cr;
constexpr int SMEM_BYTES = SMEM_F * 4;

__global__ __launch_bounds__(128) void k_reduce_stats(
    const float* __restrict__ X, const float* __restrict__ w_reduce,
    const float* __restrict__ b_reduce, float* __restrict__ partial)
{
    __shared__ float wr[WR_F];
    __shared__ float brd[Cr];
    __shared__ float tmp[2][32];
    const int t = threadIdx.x;
    for (int i = t; i < WR_F; i += 128) wr[i] = w_reduce[i];
    if (t < Cr) brd[t] = b_reduce[t];
    __syncthreads();
    const int p  = blockIdx.x * 128 + t;
    const int b  = p >> 14;
    const int hw = p & (HW - 1);
    const float* xb = X + b * CHW + hw;
    float r[Cr];
    #pragma unroll
    for (int o = 0; o < Cr; ++o) r[o] = brd[o];
    #pragma unroll 4
    for (int c = 0; c < C; ++c) {
        const float x = xb[c * HW];
        #pragma unroll
        for (int o = 0; o < Cr; ++o) r[o] = fmaf(x, wr[o * C + c], r[o]);
    }
    const int lane = t & 63, wv = t >> 6;
    #pragma unroll
    for (int o = 0; o < Cr; ++o) {
        float s = r[o], q = r[o] * r[o];
        #pragma unroll
        for (int off = 32; off > 0; off >>= 1) {
            s += __shfl_down(s, off);
            q += __shfl_down(q, off);
        }
        if (lane == 0) { tmp[wv][o] = s; tmp[wv][Cr + o] = q; }
    }
    __syncthreads();
    if (t < 32) partial[blockIdx.x * 32 + t] = tmp[0][t] + tmp[1][t];
}

__global__ __launch_bounds__(256) void k_stats_final(
    const float* __restrict__ partial, float* __restrict__ stats)
{
    __shared__ float red[256];
    __shared__ float fin[32];
    const int t = threadIdx.x;
    const int o = t & 31, g = t >> 5;
    float acc = 0.f;
    #pragma unroll 8
    for (int j = 0; j < 32; ++j) acc += partial[(g * 32 + j) * 32 + o];
    red[t] = acc;
    __syncthreads();
    if (t < 32) {
        float v = 0.f;
        #pragma unroll
        for (int g2 = 0; g2 < 8; ++g2) v += red[g2 * 32 + t];
        fin[t] = v;
    }
    __syncthreads();
    if (t < Cr) {
        const float mean = fin[t] / (float)NPIX;
        const float var  = fin[Cr + t] / (float)NPIX - mean * mean;
        stats[t]      = mean;
        stats[Cr + t] = rsqrtf(var + EPS);
    }
}

__global__ __launch_bounds__(256) void k_involution(
    const float* __restrict__ X, const float* __restrict__ w_reduce,
    const float* __restrict__ b_reduce, const float* __restrict__ gamma,
    const float* __restrict__ beta, const float* __restrict__ w_span,
    const float* __restrict__ b_span, const float* __restrict__ stats,
    float* __restrict__ out)
{
    extern __shared__ float smem[];
    float* Xs   = smem;
    float* kcS  = Xs  + XS_F;
    float* actS = kcS + KC_F;
    float* wrS  = actS + ACT_F;
    float* wspS = wrS + WR_F;
    float* bspS = wspS + WSP_F;
    float* scS  = bspS + KK;
    float* ofS  = scS + Cr;
    const int t    = threadIdx.x;
    const int bx   = blockIdx.x;
    const int b    = bx >> 8;
    const int tile = bx & 255;
    const int h0   = (tile >> 4) << 3;
    const int w0   = (tile & 15) << 3;
    const float* xbg = X + b * CHW;
    for (int idx = t; idx < XS_F; idx += 256) {
        const int c   = idx / 196;
        const int rem = idx - c * 196;
        const int r   = rem / 14;
        const int col = rem - r * 14;
        const int gh  = h0 + r - 3, gw = w0 + col - 3;
        float v = 0.f;
        if ((unsigned)gh < (unsigned)H && (unsigned)gw < (unsigned)W)
            v = xbg[c * HW + gh * W + gw];
        Xs[idx] = v;
    }
    for (int i = t; i < WR_F;  i += 256) wrS[i]  = w_reduce[i];
    for (int i = t; i < WSP_F; i += 256) wspS[i] = w_span[i];
    if (t < KK) bspS[t] = b_span[t];
    if (t < Cr) {
        const float m  = stats[t];
        const float rs = stats[Cr + t];
        const float gm = gamma[t];
        scS[t] = gm * rs;
        ofS[t] = (b_reduce[t] - m) * gm * rs + beta[t];
    }
    __syncthreads();
    const int pix = t & 63;
    const int grp = t >> 6;
    const int ph  = pix >> 3, pw = pix & 7;
    {
        const int base = (ph + 3) * 14 + (pw + 3);
        float d0 = 0.f, d1 = 0.f, d2 = 0.f, d3 = 0.f;
        #pragma unroll 8
        for (int c = 0; c < C; ++c) {
            const float x = Xs[c * 196 + base];
            d0 = fmaf(x, wrS[(grp * 4 + 0) * C + c], d0);
            d1 = fmaf(x, wrS[(grp * 4 + 1) * C + c], d1);
            d2 = fmaf(x, wrS[(grp * 4 + 2) * C + c], d2);
            d3 = fmaf(x, wrS[(grp * 4 + 3) * C + c], d3);
        }
        const float d[4] = {d0, d1, d2, d3};
        #pragma unroll
        for (int j = 0; j < 4; ++j) {
            const int o = grp * 4 + j;
            actS[o * 64 + pix] = fmaxf(fmaf(scS[o], d[j], ofS[o]), 0.f);
        }
    }
    __syncthreads();
    for (int k = grp; k < KK; k += 4) {
        float v = bspS[k];
        #pragma unroll
        for (int o = 0; o < Cr; ++o)
            v = fmaf(actS[o * 64 + pix], wspS[k * Cr + o], v);
        kcS[k * 64 + pix] = v;
    }
    __syncthreads();
    float acc[16];
    #pragma unroll
    for (int i = 0; i < 16; ++i) acc[i] = 0.f;
    const float* xsc = Xs + grp * 16 * 196;
    #pragma unroll
    for (int k = 0; k < KK; ++k) {
        const int kh = k / 7, kw = k - (k / 7) * 7;
        const float kcv = kcS[k * 64 + pix];
        const int xoff = (ph + kh) * 14 + (pw + kw);
        #pragma unroll
        for (int i = 0; i < 16; ++i)
            acc[i] = fmaf(kcv, xsc[i * 196 + xoff], acc[i]);
    }
    float* ob = out + b * CHW + (grp * 16) * HW + (h0 + ph) * W + (w0 + pw);
    #pragma unroll
    for (int i = 0; i < 16; ++i) ob[i * HW] = acc[i];
}

// ==================== launch ====================

extern "C" void kernel_launch(void* const* d_in, const int* in_sizes, int n_in,
                              void* d_out, int out_size, void* d_ws, size_t ws_size,
                              hipStream_t stream) {
    const float* X        = (const float*)d_in[0];
    const float* w_reduce = (const float*)d_in[1];
    const float* b_reduce = (const float*)d_in[2];
    const float* gamma    = (const float*)d_in[3];
    const float* beta     = (const float*)d_in[4];
    const float* w_span   = (const float*)d_in[5];
    const float* b_span   = (const float*)d_in[6];
    float* out = (float*)d_out;
    float* ws  = (float*)d_ws;

    if (ws_size >= WS_NEED) {
        float* r_ws    = ws;
        float* partial = ws + R_F;
        float* stats   = ws + R_F + P_F;
        k_reduce_r<<<512, 256, 0, stream>>>(X, w_reduce, b_reduce, r_ws, partial);
        k_stats2<<<1, 256, 0, stream>>>(partial, gamma, beta, stats);
        k_inv_split<<<1024, 256, 0, stream>>>(X, r_ws, stats, w_span, b_span, out);
    } else {
        float* partial = ws;
        float* stats   = ws + 8192;
        hipFuncSetAttribute((const void*)k_involution,
                            hipFuncAttributeMaxDynamicSharedMemorySize, SMEM_BYTES);
        k_reduce_stats<<<256, 128, 0, stream>>>(X, w_reduce, b_reduce, partial);
        k_stats_final<<<1, 256, 0, stream>>>(partial, stats);
        k_involution<<<512, 256, SMEM_BYTES, stream>>>(
            X, w_reduce, b_reduce, gamma, beta, w_span, b_span, stats, out);
    }
}